// Round 2
// baseline (651.511 us; speedup 1.0000x reference)
//
#include <hip/hip_runtime.h>

#define IN_CH 1024
#define INTER 512
#define NEXP  128
#define TPE   512

typedef __bf16 bf16x8  __attribute__((ext_vector_type(8)));
typedef __bf16 bf16x4v __attribute__((ext_vector_type(4)));
typedef float  f32x4   __attribute__((ext_vector_type(4)));

// ---------------- Kernel A: h = silu(x@w1^T + b1) * (x@w3^T + b3) ------------
// 512 threads / 8 waves (4x2), BM=BN=128, BK=64, T14 split staging:
// issue loads(t+1) -> MFMA(t) -> barrier -> cvt+ds_write(t+1) -> barrier.
__global__ __launch_bounds__(512) void moe_h_kernel(
    const float* __restrict__ x, const int* __restrict__ idxs,
    const float* __restrict__ w1w, const float* __restrict__ w1b,
    const float* __restrict__ w3w, const float* __restrict__ w3b,
    __bf16* __restrict__ hbuf)
{
  __shared__ __align__(16) ushort sA[128*64];
  __shared__ __align__(16) ushort sB1[128*64];
  __shared__ __align__(16) ushort sB3[128*64];

  // XCD swizzle: 2048 blocks, 256/XCD -> each expert's 16 tiles on one XCD
  const int blk = (blockIdx.x & 7) * (NEXP*16/8) + (blockIdx.x >> 3);
  const int e   = blk >> 4;
  const int tl  = blk & 15;
  const int tm  = tl >> 2, tn = tl & 3;

  const int tid  = threadIdx.x;
  const int lane = tid & 63;
  const int wid  = tid >> 6;       // 0..7
  const int wm   = wid >> 1;       // 0..3 -> 32-row slice
  const int wn   = wid & 1;        // 0..1 -> 64-col slice

  // staging: thread handles rows r0+32i (i=0..3), float4-col c4 per tile
  const int r0 = tid >> 4;   // 0..31
  const int c4 = tid & 15;   // 0..15

  const float* aptr[4];
#pragma unroll
  for (int i = 0; i < 4; ++i) {
    const int tok = idxs[e*TPE + tm*128 + r0 + 32*i];
    aptr[i] = x + (size_t)tok*IN_CH + (c4<<2);
  }
  const float* b1p = w1w + ((size_t)e*INTER + tn*128 + r0)*IN_CH + (c4<<2);
  const float* b3p = w3w + ((size_t)e*INTER + tn*128 + r0)*IN_CH + (c4<<2);

  // swizzled LDS write offset (ushort units); (r&7) == (r0&7) since rows step 32
  const int swz = ((((c4>>1) ^ (r0&7))<<3) | ((c4&1)<<2));

  f32x4 acc1[2][4], acc3[2][4];
#pragma unroll
  for (int a = 0; a < 2; ++a)
#pragma unroll
    for (int b = 0; b < 4; ++b) {
      acc1[a][b] = (f32x4){0.f,0.f,0.f,0.f};
      acc3[a][b] = (f32x4){0.f,0.f,0.f,0.f};
    }

  float4 xv[4], v1[4], v3[4];

  auto loads = [&](int kof) {
#pragma unroll
    for (int i = 0; i < 4; ++i) {
      xv[i] = *(const float4*)(aptr[i] + kof);
      v1[i] = *(const float4*)(b1p + (size_t)(32*i)*IN_CH + kof);
      v3[i] = *(const float4*)(b3p + (size_t)(32*i)*IN_CH + kof);
    }
  };
  auto stores = [&]() {
#pragma unroll
    for (int i = 0; i < 4; ++i) {
      const int ro = (r0 + 32*i)*64 + swz;
      bf16x4v a, b, c;
      a[0]=(__bf16)xv[i].x; a[1]=(__bf16)xv[i].y; a[2]=(__bf16)xv[i].z; a[3]=(__bf16)xv[i].w;
      b[0]=(__bf16)v1[i].x; b[1]=(__bf16)v1[i].y; b[2]=(__bf16)v1[i].z; b[3]=(__bf16)v1[i].w;
      c[0]=(__bf16)v3[i].x; c[1]=(__bf16)v3[i].y; c[2]=(__bf16)v3[i].z; c[3]=(__bf16)v3[i].w;
      *(bf16x4v*)&sA [ro] = a;
      *(bf16x4v*)&sB1[ro] = b;
      *(bf16x4v*)&sB3[ro] = c;
    }
  };
  auto mfma_tile = [&]() {
#pragma unroll
    for (int ks = 0; ks < 2; ++ks) {
      bf16x8 af[2], bq[4], bt[4];
      const int k8 = (ks<<2) + (lane>>4);
#pragma unroll
      for (int mi = 0; mi < 2; ++mi) {
        const int r = wm*32 + mi*16 + (lane&15);
        af[mi] = *(const bf16x8*)&sA[r*64 + ((k8 ^ (r&7))<<3)];
      }
#pragma unroll
      for (int ni = 0; ni < 4; ++ni) {
        const int r   = wn*64 + ni*16 + (lane&15);
        const int off = r*64 + ((k8 ^ (r&7))<<3);
        bq[ni] = *(const bf16x8*)&sB1[off];
        bt[ni] = *(const bf16x8*)&sB3[off];
      }
#pragma unroll
      for (int mi = 0; mi < 2; ++mi)
#pragma unroll
        for (int ni = 0; ni < 4; ++ni) {
          acc1[mi][ni] = __builtin_amdgcn_mfma_f32_16x16x32_bf16(af[mi], bq[ni], acc1[mi][ni], 0, 0, 0);
          acc3[mi][ni] = __builtin_amdgcn_mfma_f32_16x16x32_bf16(af[mi], bt[ni], acc3[mi][ni], 0, 0, 0);
        }
    }
  };

  // prologue: stage tile 0
  loads(0);
  stores();
  __syncthreads();

  for (int kt = 0; kt < IN_CH/64 - 1; ++kt) {
    loads((kt+1)*64);     // VMEM in flight during MFMA
    mfma_tile();
    __syncthreads();      // all waves done reading LDS
    stores();             // cvt + ds_write next tile
    __syncthreads();
  }
  mfma_tile();

  // epilogue: bias + SwiGLU, store bf16 h tile
  const int rowbase = tm*128 + wm*32;
  const int colbase = tn*128 + wn*64;
#pragma unroll
  for (int ni = 0; ni < 4; ++ni) {
    const int fc = colbase + ni*16 + (lane&15);
    const float b1v = w1b[e*INTER + fc];
    const float b3v = w3b[e*INTER + fc];
#pragma unroll
    for (int mi = 0; mi < 2; ++mi) {
#pragma unroll
      for (int j = 0; j < 4; ++j) {
        const int rl = rowbase + mi*16 + ((lane>>4)<<2) + j;
        const float h1 = acc1[mi][ni][j] + b1v;
        const float h3 = acc3[mi][ni][j] + b3v;
        const float s  = h1 / (1.0f + __expf(-h1));
        hbuf[((size_t)e*TPE + rl)*INTER + fc] = (__bf16)(s * h3);
      }
    }
  }
}

// ---------------- Kernel B: out = h @ w2^T + b2, scattered via idxs ----------
// 512 threads / 8 waves (4x2), BM=128 tok, BN=128 ch, BK=64, T14 split.
__global__ __launch_bounds__(512) void moe_out_kernel(
    const __bf16* __restrict__ hbuf, const float* __restrict__ w2w,
    const float* __restrict__ w2b, const int* __restrict__ idxs,
    float* __restrict__ out)
{
  __shared__ __align__(16) ushort sA[128*64];
  __shared__ __align__(16) ushort sB[128*64];

  // XCD swizzle: 4096 blocks, 512/XCD
  const int blk = (blockIdx.x & 7) * (NEXP*32/8) + (blockIdx.x >> 3);
  const int e   = blk >> 5;
  const int tl  = blk & 31;
  const int tm  = tl >> 3, tn = tl & 7;

  const int tid  = threadIdx.x;
  const int lane = tid & 63;
  const int wid  = tid >> 6;
  const int wm   = wid >> 1;       // 0..3
  const int wn   = wid & 1;        // 0..1

  // A (h, bf16): 1024 chunks / 512 threads -> rows rA, rA+64, chunk c8
  const int rA   = tid >> 3;          // 0..63
  const int c8   = tid & 7;           // 0..7
  const int swzA = ((c8 ^ (rA&7))<<3);
  const __bf16* ap = hbuf + ((size_t)e*TPE + tm*128 + rA)*INTER + (c8<<3);

  // B (w2, fp32 -> bf16): rows r0+32i (i=0..3), float4-col c4
  const int r0   = tid >> 4;          // 0..31
  const int c4   = tid & 15;
  const int swzB = ((((c4>>1) ^ (r0&7))<<3) | ((c4&1)<<2));
  const float* bp = w2w + ((size_t)e*IN_CH + tn*128 + r0)*INTER + (c4<<2);

  f32x4 acc[2][4];
#pragma unroll
  for (int a = 0; a < 2; ++a)
#pragma unroll
    for (int b = 0; b < 4; ++b) acc[a][b] = (f32x4){0.f,0.f,0.f,0.f};

  uint4  hv[2];
  float4 wv[4];

  auto loads = [&](int kof) {
#pragma unroll
    for (int i = 0; i < 2; ++i)
      hv[i] = *(const uint4*)(ap + (size_t)(64*i)*INTER + kof);
#pragma unroll
    for (int i = 0; i < 4; ++i)
      wv[i] = *(const float4*)(bp + (size_t)(32*i)*INTER + kof);
  };
  auto stores = [&]() {
#pragma unroll
    for (int i = 0; i < 2; ++i)
      *(uint4*)&sA[(rA + 64*i)*64 + swzA] = hv[i];
#pragma unroll
    for (int i = 0; i < 4; ++i) {
      bf16x4v b;
      b[0]=(__bf16)wv[i].x; b[1]=(__bf16)wv[i].y; b[2]=(__bf16)wv[i].z; b[3]=(__bf16)wv[i].w;
      *(bf16x4v*)&sB[(r0 + 32*i)*64 + swzB] = b;
    }
  };
  auto mfma_tile = [&]() {
#pragma unroll
    for (int ks = 0; ks < 2; ++ks) {
      bf16x8 af[2], bf[4];
      const int k8 = (ks<<2) + (lane>>4);
#pragma unroll
      for (int mi = 0; mi < 2; ++mi) {
        const int r = wm*32 + mi*16 + (lane&15);
        af[mi] = *(const bf16x8*)&sA[r*64 + ((k8 ^ (r&7))<<3)];
      }
#pragma unroll
      for (int ni = 0; ni < 4; ++ni) {
        const int r = wn*64 + ni*16 + (lane&15);
        bf[ni] = *(const bf16x8*)&sB[r*64 + ((k8 ^ (r&7))<<3)];
      }
#pragma unroll
      for (int mi = 0; mi < 2; ++mi)
#pragma unroll
        for (int ni = 0; ni < 4; ++ni)
          acc[mi][ni] = __builtin_amdgcn_mfma_f32_16x16x32_bf16(af[mi], bf[ni], acc[mi][ni], 0, 0, 0);
    }
  };

  loads(0);
  stores();
  __syncthreads();

  for (int kt = 0; kt < INTER/64 - 1; ++kt) {
    loads((kt+1)*64);
    mfma_tile();
    __syncthreads();
    stores();
    __syncthreads();
  }
  mfma_tile();

  // epilogue: bias + scatter to original token positions (fp32)
  const int rowbase = tm*128 + wm*32;
  const int colbase = tn*128 + wn*64;
  float b2v[4];
#pragma unroll
  for (int ni = 0; ni < 4; ++ni)
    b2v[ni] = w2b[e*IN_CH + colbase + ni*16 + (lane&15)];
#pragma unroll
  for (int mi = 0; mi < 2; ++mi) {
#pragma unroll
    for (int j = 0; j < 4; ++j) {
      const int rl  = rowbase + mi*16 + ((lane>>4)<<2) + j;
      const int tok = idxs[e*TPE + rl];
      float* orow = out + (size_t)tok*IN_CH;
#pragma unroll
      for (int ni = 0; ni < 4; ++ni)
        orow[colbase + ni*16 + (lane&15)] = acc[mi][ni][j] + b2v[ni];
    }
  }
}

extern "C" void kernel_launch(void* const* d_in, const int* in_sizes, int n_in,
                              void* d_out, int out_size, void* d_ws, size_t ws_size,
                              hipStream_t stream) {
  const float* x    = (const float*)d_in[0];
  const int*   idxs = (const int*)d_in[1];
  const float* w1w  = (const float*)d_in[2];
  const float* w1b  = (const float*)d_in[3];
  const float* w2w  = (const float*)d_in[4];
  const float* w2b  = (const float*)d_in[5];
  const float* w3w  = (const float*)d_in[6];
  const float* w3b  = (const float*)d_in[7];
  float*  out  = (float*)d_out;
  __bf16* hbuf = (__bf16*)d_ws;   // 128*512*512 bf16 = 64 MB intermediate

  moe_h_kernel<<<dim3(NEXP*16), dim3(512), 0, stream>>>(x, idxs, w1w, w1b, w3w, w3b, hbuf);
  moe_out_kernel<<<dim3(NEXP*32), dim3(512), 0, stream>>>(hbuf, w2w, w2b, idxs, out);
}

// Round 3
// 490.471 us; speedup vs baseline: 1.3283x; 1.3283x over previous
//
#include <hip/hip_runtime.h>

#define IN_CH 1024
#define INTER 512
#define NEXP  128
#define TPE   512

typedef __bf16 bf16x8  __attribute__((ext_vector_type(8)));
typedef __bf16 bf16x4v __attribute__((ext_vector_type(4)));
typedef float  f32x4   __attribute__((ext_vector_type(4)));

// ---------------- Kernel A: h = silu(x@w1^T + b1) * (x@w3^T + b3) ------------
// 512 threads / 8 waves (4x2), BM=BN=128, BK=64.
// Double-buffered LDS, ONE raw s_barrier per K-step, loads(t+2) in flight
// across the barrier (no vmcnt(0) drain at barrier -> true pipeline).
__global__ __launch_bounds__(512) void moe_h_kernel(
    const float* __restrict__ x, const int* __restrict__ idxs,
    const float* __restrict__ w1w, const float* __restrict__ w1b,
    const float* __restrict__ w3w, const float* __restrict__ w3b,
    __bf16* __restrict__ hbuf)
{
  __shared__ __align__(16) ushort sA [2][128*64];
  __shared__ __align__(16) ushort sB1[2][128*64];
  __shared__ __align__(16) ushort sB3[2][128*64];   // 96 KB total

  // XCD swizzle: 2048 blocks, 256/XCD -> each expert's 16 tiles on one XCD
  const int blk = (blockIdx.x & 7) * (NEXP*16/8) + (blockIdx.x >> 3);
  const int e   = blk >> 4;
  const int tl  = blk & 15;
  const int tm  = tl >> 2, tn = tl & 3;

  const int tid  = threadIdx.x;
  const int lane = tid & 63;
  const int wid  = tid >> 6;       // 0..7
  const int wm   = wid >> 1;       // 0..3 -> 32-row slice
  const int wn   = wid & 1;        // 0..1 -> 64-col slice

  const int r0 = tid >> 4;   // 0..31
  const int c4 = tid & 15;   // 0..15

  const float* aptr[4];
#pragma unroll
  for (int i = 0; i < 4; ++i) {
    const int tok = idxs[e*TPE + tm*128 + r0 + 32*i];
    aptr[i] = x + (size_t)tok*IN_CH + (c4<<2);
  }
  const float* b1p = w1w + ((size_t)e*INTER + tn*128 + r0)*IN_CH + (c4<<2);
  const float* b3p = w3w + ((size_t)e*INTER + tn*128 + r0)*IN_CH + (c4<<2);

  const int swz = ((((c4>>1) ^ (r0&7))<<3) | ((c4&1)<<2));

  f32x4 acc1[2][4], acc3[2][4];
#pragma unroll
  for (int a = 0; a < 2; ++a)
#pragma unroll
    for (int b = 0; b < 4; ++b) {
      acc1[a][b] = (f32x4){0.f,0.f,0.f,0.f};
      acc3[a][b] = (f32x4){0.f,0.f,0.f,0.f};
    }

  float4 xv[4], v1[4], v3[4];

  auto loads = [&](int kof) {
#pragma unroll
    for (int i = 0; i < 4; ++i) {
      xv[i] = *(const float4*)(aptr[i] + kof);
      v1[i] = *(const float4*)(b1p + (size_t)(32*i)*IN_CH + kof);
      v3[i] = *(const float4*)(b3p + (size_t)(32*i)*IN_CH + kof);
    }
  };
  auto stores = [&](int buf) {
#pragma unroll
    for (int i = 0; i < 4; ++i) {
      const int ro = (r0 + 32*i)*64 + swz;
      bf16x4v a, b, c;
      a[0]=(__bf16)xv[i].x; a[1]=(__bf16)xv[i].y; a[2]=(__bf16)xv[i].z; a[3]=(__bf16)xv[i].w;
      b[0]=(__bf16)v1[i].x; b[1]=(__bf16)v1[i].y; b[2]=(__bf16)v1[i].z; b[3]=(__bf16)v1[i].w;
      c[0]=(__bf16)v3[i].x; c[1]=(__bf16)v3[i].y; c[2]=(__bf16)v3[i].z; c[3]=(__bf16)v3[i].w;
      *(bf16x4v*)&sA [buf][ro] = a;
      *(bf16x4v*)&sB1[buf][ro] = b;
      *(bf16x4v*)&sB3[buf][ro] = c;
    }
  };
  auto mfma_tile = [&](int buf) {
#pragma unroll
    for (int ks = 0; ks < 2; ++ks) {
      bf16x8 af[2], bq[4], bt[4];
      const int k8 = (ks<<2) + (lane>>4);
#pragma unroll
      for (int mi = 0; mi < 2; ++mi) {
        const int r = wm*32 + mi*16 + (lane&15);
        af[mi] = *(const bf16x8*)&sA[buf][r*64 + ((k8 ^ (r&7))<<3)];
      }
#pragma unroll
      for (int ni = 0; ni < 4; ++ni) {
        const int r   = wn*64 + ni*16 + (lane&15);
        const int off = r*64 + ((k8 ^ (r&7))<<3);
        bq[ni] = *(const bf16x8*)&sB1[buf][off];
        bt[ni] = *(const bf16x8*)&sB3[buf][off];
      }
#pragma unroll
      for (int mi = 0; mi < 2; ++mi)
#pragma unroll
        for (int ni = 0; ni < 4; ++ni) {
          acc1[mi][ni] = __builtin_amdgcn_mfma_f32_16x16x32_bf16(af[mi], bq[ni], acc1[mi][ni], 0, 0, 0);
          acc3[mi][ni] = __builtin_amdgcn_mfma_f32_16x16x32_bf16(af[mi], bt[ni], acc3[mi][ni], 0, 0, 0);
        }
    }
  };

  // prologue: tile0 -> buf0; prefetch tile1 into regs
  loads(0);
  stores(0);                 // compiler inserts vmcnt wait before cvt
  loads(64);                 // tile 1 in flight
  asm volatile("s_waitcnt lgkmcnt(0)" ::: "memory");
  __builtin_amdgcn_s_barrier();

  int cur = 0;
  for (int kt = 0; kt < IN_CH/64; ++kt) {
    if (kt < IN_CH/64 - 1) {
      stores(cur ^ 1);                       // regs(t+1): waits vmcnt here only
      if (kt < IN_CH/64 - 2) loads((kt+2)*64); // t+2 rides across the barrier
    }
    __builtin_amdgcn_s_setprio(1);
    mfma_tile(cur);
    __builtin_amdgcn_s_setprio(0);
    asm volatile("s_waitcnt lgkmcnt(0)" ::: "memory");
    __builtin_amdgcn_s_barrier();
    cur ^= 1;
  }

  // epilogue: bias + SwiGLU, store bf16 h tile
  const int rowbase = tm*128 + wm*32;
  const int colbase = tn*128 + wn*64;
#pragma unroll
  for (int ni = 0; ni < 4; ++ni) {
    const int fc = colbase + ni*16 + (lane&15);
    const float b1v = w1b[e*INTER + fc];
    const float b3v = w3b[e*INTER + fc];
#pragma unroll
    for (int mi = 0; mi < 2; ++mi) {
#pragma unroll
      for (int j = 0; j < 4; ++j) {
        const int rl = rowbase + mi*16 + ((lane>>4)<<2) + j;
        const float h1 = acc1[mi][ni][j] + b1v;
        const float h3 = acc3[mi][ni][j] + b3v;
        const float s  = h1 / (1.0f + __expf(-h1));
        hbuf[((size_t)e*TPE + rl)*INTER + fc] = (__bf16)(s * h3);
      }
    }
  }
}

// ---------------- Kernel B: out = h @ w2^T + b2, scattered via idxs ----------
// Same pipeline structure; K = 512 (8 steps of 64).
__global__ __launch_bounds__(512) void moe_out_kernel(
    const __bf16* __restrict__ hbuf, const float* __restrict__ w2w,
    const float* __restrict__ w2b, const int* __restrict__ idxs,
    float* __restrict__ out)
{
  __shared__ __align__(16) ushort sA[2][128*64];
  __shared__ __align__(16) ushort sB[2][128*64];   // 64 KB total

  const int blk = (blockIdx.x & 7) * (NEXP*32/8) + (blockIdx.x >> 3);
  const int e   = blk >> 5;
  const int tl  = blk & 31;
  const int tm  = tl >> 3, tn = tl & 7;

  const int tid  = threadIdx.x;
  const int lane = tid & 63;
  const int wid  = tid >> 6;
  const int wm   = wid >> 1;       // 0..3
  const int wn   = wid & 1;        // 0..1

  // A (h, bf16): rows rA, rA+64, chunk c8 (16B)
  const int rA   = tid >> 3;          // 0..63
  const int c8   = tid & 7;           // 0..7
  const int swzA = ((c8 ^ (rA&7))<<3);
  const __bf16* ap = hbuf + ((size_t)e*TPE + tm*128 + rA)*INTER + (c8<<3);

  // B (w2, fp32 -> bf16): rows r0+32i, float4-col c4
  const int r0   = tid >> 4;          // 0..31
  const int c4   = tid & 15;
  const int swzB = ((((c4>>1) ^ (r0&7))<<3) | ((c4&1)<<2));
  const float* bp = w2w + ((size_t)e*IN_CH + tn*128 + r0)*INTER + (c4<<2);

  f32x4 acc[2][4];
#pragma unroll
  for (int a = 0; a < 2; ++a)
#pragma unroll
    for (int b = 0; b < 4; ++b) acc[a][b] = (f32x4){0.f,0.f,0.f,0.f};

  uint4  hv[2];
  float4 wv[4];

  auto loads = [&](int kof) {
#pragma unroll
    for (int i = 0; i < 2; ++i)
      hv[i] = *(const uint4*)(ap + (size_t)(64*i)*INTER + kof);
#pragma unroll
    for (int i = 0; i < 4; ++i)
      wv[i] = *(const float4*)(bp + (size_t)(32*i)*INTER + kof);
  };
  auto stores = [&](int buf) {
#pragma unroll
    for (int i = 0; i < 2; ++i)
      *(uint4*)&sA[buf][(rA + 64*i)*64 + swzA] = hv[i];
#pragma unroll
    for (int i = 0; i < 4; ++i) {
      bf16x4v b;
      b[0]=(__bf16)wv[i].x; b[1]=(__bf16)wv[i].y; b[2]=(__bf16)wv[i].z; b[3]=(__bf16)wv[i].w;
      *(bf16x4v*)&sB[buf][(r0 + 32*i)*64 + swzB] = b;
    }
  };
  auto mfma_tile = [&](int buf) {
#pragma unroll
    for (int ks = 0; ks < 2; ++ks) {
      bf16x8 af[2], bf[4];
      const int k8 = (ks<<2) + (lane>>4);
#pragma unroll
      for (int mi = 0; mi < 2; ++mi) {
        const int r = wm*32 + mi*16 + (lane&15);
        af[mi] = *(const bf16x8*)&sA[buf][r*64 + ((k8 ^ (r&7))<<3)];
      }
#pragma unroll
      for (int ni = 0; ni < 4; ++ni) {
        const int r = wn*64 + ni*16 + (lane&15);
        bf[ni] = *(const bf16x8*)&sB[buf][r*64 + ((k8 ^ (r&7))<<3)];
      }
#pragma unroll
      for (int mi = 0; mi < 2; ++mi)
#pragma unroll
        for (int ni = 0; ni < 4; ++ni)
          acc[mi][ni] = __builtin_amdgcn_mfma_f32_16x16x32_bf16(af[mi], bf[ni], acc[mi][ni], 0, 0, 0);
    }
  };

  loads(0);
  stores(0);
  loads(64);
  asm volatile("s_waitcnt lgkmcnt(0)" ::: "memory");
  __builtin_amdgcn_s_barrier();

  int cur = 0;
  for (int kt = 0; kt < INTER/64; ++kt) {
    if (kt < INTER/64 - 1) {
      stores(cur ^ 1);
      if (kt < INTER/64 - 2) loads((kt+2)*64);
    }
    __builtin_amdgcn_s_setprio(1);
    mfma_tile(cur);
    __builtin_amdgcn_s_setprio(0);
    asm volatile("s_waitcnt lgkmcnt(0)" ::: "memory");
    __builtin_amdgcn_s_barrier();
    cur ^= 1;
  }

  // epilogue: bias + scatter to original token positions (fp32)
  const int rowbase = tm*128 + wm*32;
  const int colbase = tn*128 + wn*64;
  float b2v[4];
#pragma unroll
  for (int ni = 0; ni < 4; ++ni)
    b2v[ni] = w2b[e*IN_CH + colbase + ni*16 + (lane&15)];
#pragma unroll
  for (int mi = 0; mi < 2; ++mi) {
#pragma unroll
    for (int j = 0; j < 4; ++j) {
      const int rl  = rowbase + mi*16 + ((lane>>4)<<2) + j;
      const int tok = idxs[e*TPE + rl];
      float* orow = out + (size_t)tok*IN_CH;
#pragma unroll
      for (int ni = 0; ni < 4; ++ni)
        orow[colbase + ni*16 + (lane&15)] = acc[mi][ni][j] + b2v[ni];
    }
  }
}

extern "C" void kernel_launch(void* const* d_in, const int* in_sizes, int n_in,
                              void* d_out, int out_size, void* d_ws, size_t ws_size,
                              hipStream_t stream) {
  const float* x    = (const float*)d_in[0];
  const int*   idxs = (const int*)d_in[1];
  const float* w1w  = (const float*)d_in[2];
  const float* w1b  = (const float*)d_in[3];
  const float* w2w  = (const float*)d_in[4];
  const float* w2b  = (const float*)d_in[5];
  const float* w3w  = (const float*)d_in[6];
  const float* w3b  = (const float*)d_in[7];
  float*  out  = (float*)d_out;
  __bf16* hbuf = (__bf16*)d_ws;   // 128*512*512 bf16 = 64 MB intermediate

  moe_h_kernel<<<dim3(NEXP*16), dim3(512), 0, stream>>>(x, idxs, w1w, w1b, w3w, w3b, hbuf);
  moe_out_kernel<<<dim3(NEXP*32), dim3(512), 0, stream>>>(hbuf, w2w, w2b, idxs, out);
}